// Round 5
// baseline (12463.918 us; speedup 1.0000x reference)
//
#include <hip/hip_runtime.h>

// ---------------------------------------------------------------------------
// Problem constants (B=16, N=128, FIN=D=512)
// ---------------------------------------------------------------------------
#define BATCH 16
#define NNODE 128
#define DIM 512
#define NP1 129              // N+1 (with virtual node)
#define EDSZ (NP1 * NP1)     // 16641 per batch
#define LSN 256              // LSAP problem size (n+m)
#define INF_COST 10000.0f
#define ECS_LD 132           // LDS row stride (multiple of 4 for b128 alignment)
#define BIGF 3.0e38f         // sentinel (finite, packable)

// ---------------------------------------------------------------------------
// GEMM (NT): Y[m][n] = relu( sum_k A[m][k] * W[n][k] + bias[n] )
// ---------------------------------------------------------------------------
__global__ __launch_bounds__(256) void gemm_nt_relu(
    const float* __restrict__ A, const float* __restrict__ W,
    const float* __restrict__ bias, float* __restrict__ Y,
    int M, int N, int K) {
  __shared__ float sA[16][65];
  __shared__ float sB[16][65];
  const int tid = threadIdx.x;
  const int m0 = blockIdx.x * 64;
  const int n0 = blockIdx.y * 64;
  const int tm = tid / 16, tn = tid % 16;
  const int lr = tid / 4;
  const int lk = (tid % 4) * 4;
  float acc[4][4] = {};
  for (int k0 = 0; k0 < K; k0 += 16) {
    float4 av = *(const float4*)(A + (size_t)(m0 + lr) * K + k0 + lk);
    float4 wv = *(const float4*)(W + (size_t)(n0 + lr) * K + k0 + lk);
    sA[lk + 0][lr] = av.x; sA[lk + 1][lr] = av.y;
    sA[lk + 2][lr] = av.z; sA[lk + 3][lr] = av.w;
    sB[lk + 0][lr] = wv.x; sB[lk + 1][lr] = wv.y;
    sB[lk + 2][lr] = wv.z; sB[lk + 3][lr] = wv.w;
    __syncthreads();
#pragma unroll
    for (int k = 0; k < 16; ++k) {
      float a[4], b[4];
#pragma unroll
      for (int q = 0; q < 4; ++q) { a[q] = sA[k][tm * 4 + q]; b[q] = sB[k][tn * 4 + q]; }
#pragma unroll
      for (int i = 0; i < 4; ++i)
#pragma unroll
        for (int j = 0; j < 4; ++j) acc[i][j] = fmaf(a[i], b[j], acc[i][j]);
    }
    __syncthreads();
  }
#pragma unroll
  for (int i = 0; i < 4; ++i) {
    int m = m0 + tm * 4 + i;
#pragma unroll
    for (int j = 0; j < 4; ++j) {
      int n = n0 + tn * 4 + j;
      Y[(size_t)m * N + n] = fmaxf(acc[i][j] + bias[n], 0.f);
    }
  }
}

// ---------------------------------------------------------------------------
// Single-row embed (virtual node)
// ---------------------------------------------------------------------------
__global__ __launch_bounds__(256) void vec_gemm_relu(
    const float* __restrict__ x, const float* __restrict__ W,
    const float* __restrict__ bias, float* __restrict__ y) {
  __shared__ float sx[DIM];
  for (int k = threadIdx.x; k < DIM; k += 256) sx[k] = x[k];
  __syncthreads();
  for (int n = threadIdx.x; n < DIM; n += 256) {
    const float* w = W + (size_t)n * DIM;
    float s = 0.f;
    for (int k = 0; k < DIM; k += 4) {
      float4 wv = *(const float4*)(w + k);
      s = fmaf(sx[k + 0], wv.x, s);
      s = fmaf(sx[k + 1], wv.y, s);
      s = fmaf(sx[k + 2], wv.z, s);
      s = fmaf(sx[k + 3], wv.w, s);
    }
    y[n] = fmaxf(s + bias[n], 0.f);
  }
}

// ---------------------------------------------------------------------------
// cdist: d[b][i][j] = || esrow(b,i) - etrow(b,j) ||_2
// ---------------------------------------------------------------------------
__global__ __launch_bounds__(256) void cdist_kernel(
    const float* __restrict__ es, const float* __restrict__ et,
    const float* __restrict__ ev, float* __restrict__ d) {
  const int b = blockIdx.z;
  const int i0 = blockIdx.x * 32;
  const int j0 = blockIdx.y * 32;
  __shared__ float sA[32][33];
  __shared__ float sB[32][33];
  const int tid = threadIdx.x;
  const int ty = tid / 16, tx = tid % 16;
  const int lr = tid / 8;
  const int lk4 = (tid % 8) * 4;
  const int gi = i0 + lr;
  const int gj = j0 + lr;
  const float* pa = (gi < NNODE) ? (es + ((size_t)b * NNODE + gi) * DIM) : ev;
  const float* pb = (gj < NNODE) ? (et + ((size_t)b * NNODE + gj) * DIM) : ev;
  float acc[2][2] = {};
  for (int k0 = 0; k0 < DIM; k0 += 32) {
    float4 av = *(const float4*)(pa + k0 + lk4);
    float4 bv = *(const float4*)(pb + k0 + lk4);
    sA[lr][lk4 + 0] = av.x; sA[lr][lk4 + 1] = av.y;
    sA[lr][lk4 + 2] = av.z; sA[lr][lk4 + 3] = av.w;
    sB[lr][lk4 + 0] = bv.x; sB[lr][lk4 + 1] = bv.y;
    sB[lr][lk4 + 2] = bv.z; sB[lr][lk4 + 3] = bv.w;
    __syncthreads();
#pragma unroll 8
    for (int k = 0; k < 32; ++k) {
      float a0 = sA[ty * 2 + 0][k], a1 = sA[ty * 2 + 1][k];
      float b0 = sB[tx * 2 + 0][k], b1 = sB[tx * 2 + 1][k];
      float d00 = a0 - b0, d01 = a0 - b1, d10 = a1 - b0, d11 = a1 - b1;
      acc[0][0] = fmaf(d00, d00, acc[0][0]);
      acc[0][1] = fmaf(d01, d01, acc[0][1]);
      acc[1][0] = fmaf(d10, d10, acc[1][0]);
      acc[1][1] = fmaf(d11, d11, acc[1][1]);
    }
    __syncthreads();
  }
#pragma unroll
  for (int i = 0; i < 2; ++i) {
    int gi2 = i0 + ty * 2 + i;
#pragma unroll
    for (int j = 0; j < 2; ++j) {
      int gj2 = j0 + tx * 2 + j;
      if (gi2 < NP1 && gj2 < NP1)
        d[(size_t)b * EDSZ + gi2 * NP1 + gj2] = sqrtf(acc[i][j]);
    }
  }
}

// ---------------------------------------------------------------------------
// Deterministic per-batch sum (fp64 tree)
// ---------------------------------------------------------------------------
__global__ __launch_bounds__(256) void batch_sum(
    const float* __restrict__ d, float* __restrict__ sums) {
  const int b = blockIdx.x;
  double s = 0.0;
  for (int idx = threadIdx.x; idx < EDSZ; idx += 256)
    s += (double)d[(size_t)b * EDSZ + idx];
  __shared__ double red[256];
  red[threadIdx.x] = s;
  __syncthreads();
  for (int off = 128; off; off >>= 1) {
    if (threadIdx.x < off) red[threadIdx.x] += red[threadIdx.x + off];
    __syncthreads();
  }
  if (threadIdx.x == 0) sums[b] = (float)red[0];
}

// ---------------------------------------------------------------------------
// normalize: edit = d / sum[b] * N*N
// ---------------------------------------------------------------------------
__global__ __launch_bounds__(256) void normalize_kernel(
    const float* __restrict__ d, const float* __restrict__ sums,
    float* __restrict__ edit) {
  int idx = blockIdx.x * 256 + threadIdx.x;
  if (idx < BATCH * EDSZ) {
    int b = idx / EDSZ;
    edit[idx] = d[idx] / sums[b] * (float)(NNODE * NNODE);
  }
}

// ---------------------------------------------------------------------------
// cross-lane helpers: VALU-pipe (DPP / readlane)
// ---------------------------------------------------------------------------
// Packed (value,col): hi32 = f32 bits of nonneg value, lo32 = column id.
// v_min_f64 on this packing = min by value, ties -> lowest column.
__device__ __forceinline__ double pack_mc(float m, unsigned col) {
  union { double d; unsigned u[2]; } r;
  r.u[0] = col;
  r.u[1] = __float_as_uint(m);
  return r.d;
}

template <int CTRL>
__device__ __forceinline__ double dpp_min_step_pk(double x) {
  union { double d; unsigned long long q; int i[2]; } s, o, r;
  s.d = x;
  o.q = 0x7FEFFFFFFFFFFFFFULL;  // max finite double: identity for packed min
  r.i[0] = __builtin_amdgcn_update_dpp(o.i[0], s.i[0], CTRL, 0xf, 0xf, false);
  r.i[1] = __builtin_amdgcn_update_dpp(o.i[1], s.i[1], CTRL, 0xf, 0xf, false);
  return fmin(x, r.d);
}

// wave64 packed argmin: returns (delta, col) of the global min, uniform.
__device__ __forceinline__ void wave_argmin_pk(double x, float& delta, int& col) {
  x = dpp_min_step_pk<0x111>(x);  // row_shr:1
  x = dpp_min_step_pk<0x112>(x);  // row_shr:2
  x = dpp_min_step_pk<0x114>(x);  // row_shr:4
  x = dpp_min_step_pk<0x118>(x);  // row_shr:8
  x = dpp_min_step_pk<0x142>(x);  // row_bcast:15
  x = dpp_min_step_pk<0x143>(x);  // row_bcast:31
  union { double d; int i[2]; } s;
  s.d = x;
  col = __builtin_amdgcn_readlane(s.i[0], 63);
  delta = __uint_as_float((unsigned)__builtin_amdgcn_readlane(s.i[1], 63));
}

__device__ __forceinline__ float fsel4(float a0, float a1, float a2, float a3,
                                       int s) {
  return (s == 0) ? a0 : (s == 1) ? a1 : (s == 2) ? a2 : a3;
}
__device__ __forceinline__ int isel4(int a0, int a1, int a2, int a3, int s) {
  return (s == 0) ? a0 : (s == 1) ? a1 : (s == 2) ? a2 : a3;
}

// ---------------------------------------------------------------------------
// LSAPE: LAPJV-style column reduction + shortest-augmenting-path phase.
// ONE WAVE per batch, all state in fp32 registers, VALU-pipe cross-lane ops.
// Correctness: any exact optimum yields the reference A (virtual-virtual
// pairings collapse into A[128][128]:=0; deletions/insertions are forced to
// their unique finite-cost slots; real-matching optimum generically unique).
// ---------------------------------------------------------------------------
__global__ __launch_bounds__(64) void lsap_kernel(
    const float* __restrict__ edit, float* __restrict__ Aout,
    float* __restrict__ geds) {
  const int b = blockIdx.x;
  const float* ec = edit + (size_t)b * EDSZ;
  float* A = Aout + (size_t)b * EDSZ;
  const int lane = threadIdx.x;
  const int cbase = lane * 4;  // first owned column index (0-based)

  __shared__ float ecs[NP1 * ECS_LD];

  // stage edit (row stride 132 so &ecs[r*132 + 4*lane] is 16B aligned)
  for (int row = 0; row < NP1; ++row)
    for (int c = lane; c < NP1; c += 64)
      ecs[row * ECS_LD + c] = ec[row * NP1 + c];
  for (int idx = lane; idx < EDSZ; idx += 64) A[idx] = 0.f;
  __syncthreads();

  // per-lane state: 4 columns (v, minv, way, p) + 4 rows (u)
  float u0 = 0.f, u1 = 0.f, u2 = 0.f, u3 = 0.f;
  float v0, v1, v2, v3;
  float m0, m1, m2, m3;
  int w0 = 0, w1 = 0, w2 = 0, w3 = 0;
  int p0 = 0, p1 = 0, p2 = 0, p3 = 0;

  // ---------------- Phase 1: column reduction ----------------
  // v[j] = min_i C[i][j]; y[j] = argmin row (lowest on tie).
  // Real col c: candidates = ecs[0..127][c] (rows 0..127) and ecs[128][c]
  //   (row 128+c, the unique finite virtual entry).
  // Virtual col 128+s: min = 0 at row 128 (first all-zero virtual row).
  int y0, y1, y2, y3;
  if (lane < 32) {
    float c0 = BIGF, c1 = BIGF, c2 = BIGF, c3 = BIGF;
    y0 = y1 = y2 = y3 = 0;
    for (int r = 0; r <= NNODE; ++r) {
      float4 f = *(const float4*)&ecs[r * ECS_LD + cbase];
      const int base = (r < NNODE) ? r : (NNODE + cbase);  // +q added below
      const int off = (r < NNODE) ? 0 : 1;
      if (f.x < c0) { c0 = f.x; y0 = base + 0 * off; }
      if (f.y < c1) { c1 = f.y; y1 = base + 1 * off; }
      if (f.z < c2) { c2 = f.z; y2 = base + 2 * off; }
      if (f.w < c3) { c3 = f.w; y3 = base + 3 * off; }
    }
    v0 = c0; v1 = c1; v2 = c2; v3 = c3;
  } else {
    v0 = v1 = v2 = v3 = 0.f;
    y0 = y1 = y2 = y3 = NNODE;  // row 128
  }

  // Greedy assignment, j descending (LAPJV order). Virtual cols: only j=255
  // assigns (all want row 128); cols 254..128 stay free.
  unsigned long long ra0 = 0, ra1 = 0, ra2 = 0, ra3 = 0;  // row-assigned bits
  ra2 |= 1ull;                       // row 128 taken (bit 0 of rows 128..191)
  if (lane == 63) p3 = NNODE + 1;    // p[255] = row 128 (1-indexed 129)

  for (int jj = NNODE - 1; jj >= 0; --jj) {
    const int jl = jj >> 2, jq = jj & 3;
    const int i1 = __builtin_amdgcn_readlane(isel4(y0, y1, y2, y3, jq), jl);
    const int wsel = i1 >> 6, bit = i1 & 63;
    unsigned long long msk = (wsel == 0) ? ra0 : (wsel == 1) ? ra1
                            : (wsel == 2) ? ra2 : ra3;
    if (!((msk >> bit) & 1ull)) {
      msk |= 1ull << bit;
      if (wsel == 0) ra0 = msk;
      else if (wsel == 1) ra1 = msk;
      else if (wsel == 2) ra2 = msk;
      else ra3 = msk;
      if (lane == jl) {
        if (jq == 0) p0 = i1 + 1;
        else if (jq == 1) p1 = i1 + 1;
        else if (jq == 2) p2 = i1 + 1;
        else p3 = i1 + 1;
      }
    }
  }

  // ---------------- Phase 2: SAP for each free row ----------------
  for (int ii = 0; ii < LSN; ++ii) {
    {
      const int wsel = ii >> 6, bit = ii & 63;
      const unsigned long long msk = (wsel == 0) ? ra0 : (wsel == 1) ? ra1
                                    : (wsel == 2) ? ra2 : ra3;
      if ((msk >> bit) & 1ull) continue;  // row already assigned
    }
    const int i = ii + 1;

    unsigned cused = 0, rused = 0;
    m0 = m1 = m2 = m3 = BIGF;
    int j0 = 0;       // current column (0 = dummy start)
    int i0 = i;       // p[0] = i
    for (int guard = 0; guard <= LSN; ++guard) {
      // --- mark used: column j0 (skip dummy col 0) and its row i0 ---
      if (j0 > 0 && lane == ((j0 - 1) >> 2)) {
        const int q = (j0 - 1) & 3;
        cused |= 1u << q;
        if (q == 0) m0 = BIGF;
        else if (q == 1) m1 = BIGF;
        else if (q == 2) m2 = BIGF;
        else m3 = BIGF;
      }
      if (lane == ((i0 - 1) >> 2)) rused |= 1u << ((i0 - 1) & 3);

      // --- broadcast u[i0] from owning lane (i0 uniform -> readlane) ---
      const float u_i0 = __uint_as_float((unsigned)__builtin_amdgcn_readlane(
          (int)__float_as_uint(fsel4(u0, u1, u2, u3, (i0 - 1) & 3)),
          (i0 - 1) >> 2));

      // --- cost row C[i0-1][c] for this lane's 4 columns ---
      const int r = i0 - 1;
      float C0, C1, C2, C3;
      if (r < NNODE) {
        if (lane < 32) {  // columns 0..127: dense block
          float4 f = *(const float4*)&ecs[r * ECS_LD + cbase];
          C0 = f.x; C1 = f.y; C2 = f.z; C3 = f.w;
        } else {          // columns 128..255: diag ec[r][128], else INF
          const float dg = ecs[r * ECS_LD + NNODE];
          C0 = (cbase + 0 - NNODE == r) ? dg : INF_COST;
          C1 = (cbase + 1 - NNODE == r) ? dg : INF_COST;
          C2 = (cbase + 2 - NNODE == r) ? dg : INF_COST;
          C3 = (cbase + 3 - NNODE == r) ? dg : INF_COST;
        }
      } else {
        if (lane < 32) {  // diag ec[128][r-128], else INF
          const int cc = r - NNODE;
          const float dg = ecs[NNODE * ECS_LD + cc];
          C0 = (cbase + 0 == cc) ? dg : INF_COST;
          C1 = (cbase + 1 == cc) ? dg : INF_COST;
          C2 = (cbase + 2 == cc) ? dg : INF_COST;
          C3 = (cbase + 3 == cc) ? dg : INF_COST;
        } else {          // bottom-right zero block
          C0 = C1 = C2 = C3 = 0.f;
        }
      }

      // --- relax free columns; clamp >=0 keeps the packed ordering sound ---
      const bool f0 = !(cused & 1u), f1 = !(cused & 2u);
      const bool f2 = !(cused & 4u), f3 = !(cused & 8u);
      {
        float cur = fmaxf(C0 - u_i0 - v0, 0.f);
        bool up = f0 && (cur < m0);
        m0 = up ? cur : m0; w0 = up ? j0 : w0;
      }
      {
        float cur = fmaxf(C1 - u_i0 - v1, 0.f);
        bool up = f1 && (cur < m1);
        m1 = up ? cur : m1; w1 = up ? j0 : w1;
      }
      {
        float cur = fmaxf(C2 - u_i0 - v2, 0.f);
        bool up = f2 && (cur < m2);
        m2 = up ? cur : m2; w2 = up ? j0 : w2;
      }
      {
        float cur = fmaxf(C3 - u_i0 - v3, 0.f);
        bool up = f3 && (cur < m3);
        m3 = up ? cur : m3; w3 = up ? j0 : w3;
      }

      // --- packed local min (ties -> lowest col), then wave argmin ---
      const double P0 = pack_mc(m0, cbase + 0);
      const double P1 = pack_mc(m1, cbase + 1);
      const double P2 = pack_mc(m2, cbase + 2);
      const double P3 = pack_mc(m3, cbase + 3);
      const double loc = fmin(fmin(P0, P1), fmin(P2, P3));
      float delta; int jcol;
      wave_argmin_pk(loc, delta, jcol);
      const int j1 = jcol + 1;

      // --- dual updates (registers only) ---
      if (!f0) v0 -= delta; else m0 = fmaxf(m0 - delta, 0.f);
      if (!f1) v1 -= delta; else m1 = fmaxf(m1 - delta, 0.f);
      if (!f2) v2 -= delta; else m2 = fmaxf(m2 - delta, 0.f);
      if (!f3) v3 -= delta; else m3 = fmaxf(m3 - delta, 0.f);
      if (rused & 1u) u0 += delta;
      if (rused & 2u) u1 += delta;
      if (rused & 4u) u2 += delta;
      if (rused & 8u) u3 += delta;

      // --- next (or break on free column) ---
      const int pj1 = __builtin_amdgcn_readlane(
          isel4(p0, p1, p2, p3, (j1 - 1) & 3), (j1 - 1) >> 2);
      j0 = j1;
      if (pj1 == 0) break;
      i0 = pj1;
    }

    // --- augment along way[] chain (uniform walk via readlane) ---
    int jc = j0;
    while (jc != 0) {
      const int cl = (jc - 1) >> 2, cq = (jc - 1) & 3;
      const int jp = __builtin_amdgcn_readlane(isel4(w0, w1, w2, w3, cq), cl);
      const int js = (jp == 0) ? 1 : jp;  // safe index for speculative readlane
      const int pvr = __builtin_amdgcn_readlane(
          isel4(p0, p1, p2, p3, (js - 1) & 3), (js - 1) >> 2);
      const int pv = (jp == 0) ? i : pvr;
      if (lane == cl) {
        if (cq == 0) p0 = pv;
        else if (cq == 1) p1 = pv;
        else if (cq == 2) p2 = pv;
        else p3 = pv;
      }
      jc = jp;
    }
  }

  // --- emit A and geds: column c is assigned row p[c+1]-1 ---
  double contrib = 0.0;
  {
    const int pr[4] = {p0, p1, p2, p3};
#pragma unroll
    for (int q = 0; q < 4; ++q) {
      const int rr = pr[q] - 1, cc = cbase + q;
      const int ar = min(rr, NNODE), ac = min(cc, NNODE);
      if (!(ar == NNODE && ac == NNODE)) {
        A[ar * NP1 + ac] = 1.f;
        contrib += (double)ecs[ar * ECS_LD + ac];
      }
    }
  }
#pragma unroll
  for (int off = 32; off; off >>= 1) contrib += __shfl_xor(contrib, off);
  if (lane == 0) geds[b] = (float)(contrib / 256.0);
}

// ---------------------------------------------------------------------------
// launch
// ---------------------------------------------------------------------------
extern "C" void kernel_launch(void* const* d_in, const int* in_sizes, int n_in,
                              void* d_out, int out_size, void* d_ws, size_t ws_size,
                              hipStream_t stream) {
  const float* x_s  = (const float*)d_in[0];
  const float* x_t  = (const float*)d_in[1];
  const float* W1   = (const float*)d_in[2];
  const float* b1   = (const float*)d_in[3];
  const float* W2   = (const float*)d_in[4];
  const float* b2   = (const float*)d_in[5];
  const float* virt = (const float*)d_in[6];

  const int M = BATCH * NNODE;  // 2048

  float* ws    = (float*)d_ws;
  float* h_s   = ws;
  float* h_t   = h_s + (size_t)M * DIM;
  float* e_s   = h_t + (size_t)M * DIM;
  float* e_t   = e_s + (size_t)M * DIM;
  float* h_v   = e_t + (size_t)M * DIM;
  float* e_v   = h_v + DIM;
  float* d_raw = e_v + DIM;
  float* sums  = d_raw + (size_t)BATCH * EDSZ;

  float* Aout = (float*)d_out;
  float* edit = Aout + (size_t)BATCH * EDSZ;
  float* geds = edit + (size_t)BATCH * EDSZ;

  dim3 gblk(M / 64, DIM / 64);
  gemm_nt_relu<<<gblk, 256, 0, stream>>>(x_s, W1, b1, h_s, M, DIM, DIM);
  gemm_nt_relu<<<gblk, 256, 0, stream>>>(x_t, W1, b1, h_t, M, DIM, DIM);
  vec_gemm_relu<<<1, 256, 0, stream>>>(virt, W1, b1, h_v);
  gemm_nt_relu<<<gblk, 256, 0, stream>>>(h_s, W2, b2, e_s, M, DIM, DIM);
  gemm_nt_relu<<<gblk, 256, 0, stream>>>(h_t, W2, b2, e_t, M, DIM, DIM);
  vec_gemm_relu<<<1, 256, 0, stream>>>(h_v, W2, b2, e_v);

  cdist_kernel<<<dim3(5, 5, BATCH), 256, 0, stream>>>(e_s, e_t, e_v, d_raw);
  batch_sum<<<BATCH, 256, 0, stream>>>(d_raw, sums);
  normalize_kernel<<<(BATCH * EDSZ + 255) / 256, 256, 0, stream>>>(d_raw, sums, edit);
  lsap_kernel<<<BATCH, 64, 0, stream>>>(edit, Aout, geds);
}

// Round 6
// 1347.544 us; speedup vs baseline: 9.2494x; 9.2494x over previous
//
#include <hip/hip_runtime.h>

// ---------------------------------------------------------------------------
// Problem constants (B=16, N=128, FIN=D=512)
// ---------------------------------------------------------------------------
#define BATCH 16
#define NNODE 128
#define DIM 512
#define NP1 129              // N+1 (with virtual node)
#define EDSZ (NP1 * NP1)     // 16641 per batch
#define BIGF 3.0e38f         // sentinel (finite, packable)

// ---------------------------------------------------------------------------
// GEMM (NT): Y[m][n] = relu( sum_k A[m][k] * W[n][k] + bias[n] )
// ---------------------------------------------------------------------------
__global__ __launch_bounds__(256) void gemm_nt_relu(
    const float* __restrict__ A, const float* __restrict__ W,
    const float* __restrict__ bias, float* __restrict__ Y,
    int M, int N, int K) {
  __shared__ float sA[16][65];
  __shared__ float sB[16][65];
  const int tid = threadIdx.x;
  const int m0 = blockIdx.x * 64;
  const int n0 = blockIdx.y * 64;
  const int tm = tid / 16, tn = tid % 16;
  const int lr = tid / 4;
  const int lk = (tid % 4) * 4;
  float acc[4][4] = {};
  for (int k0 = 0; k0 < K; k0 += 16) {
    float4 av = *(const float4*)(A + (size_t)(m0 + lr) * K + k0 + lk);
    float4 wv = *(const float4*)(W + (size_t)(n0 + lr) * K + k0 + lk);
    sA[lk + 0][lr] = av.x; sA[lk + 1][lr] = av.y;
    sA[lk + 2][lr] = av.z; sA[lk + 3][lr] = av.w;
    sB[lk + 0][lr] = wv.x; sB[lk + 1][lr] = wv.y;
    sB[lk + 2][lr] = wv.z; sB[lk + 3][lr] = wv.w;
    __syncthreads();
#pragma unroll
    for (int k = 0; k < 16; ++k) {
      float a[4], b[4];
#pragma unroll
      for (int q = 0; q < 4; ++q) { a[q] = sA[k][tm * 4 + q]; b[q] = sB[k][tn * 4 + q]; }
#pragma unroll
      for (int i = 0; i < 4; ++i)
#pragma unroll
        for (int j = 0; j < 4; ++j) acc[i][j] = fmaf(a[i], b[j], acc[i][j]);
    }
    __syncthreads();
  }
#pragma unroll
  for (int i = 0; i < 4; ++i) {
    int m = m0 + tm * 4 + i;
#pragma unroll
    for (int j = 0; j < 4; ++j) {
      int n = n0 + tn * 4 + j;
      Y[(size_t)m * N + n] = fmaxf(acc[i][j] + bias[n], 0.f);
    }
  }
}

// ---------------------------------------------------------------------------
// Single-row embed (virtual node)
// ---------------------------------------------------------------------------
__global__ __launch_bounds__(256) void vec_gemm_relu(
    const float* __restrict__ x, const float* __restrict__ W,
    const float* __restrict__ bias, float* __restrict__ y) {
  __shared__ float sx[DIM];
  for (int k = threadIdx.x; k < DIM; k += 256) sx[k] = x[k];
  __syncthreads();
  for (int n = threadIdx.x; n < DIM; n += 256) {
    const float* w = W + (size_t)n * DIM;
    float s = 0.f;
    for (int k = 0; k < DIM; k += 4) {
      float4 wv = *(const float4*)(w + k);
      s = fmaf(sx[k + 0], wv.x, s);
      s = fmaf(sx[k + 1], wv.y, s);
      s = fmaf(sx[k + 2], wv.z, s);
      s = fmaf(sx[k + 3], wv.w, s);
    }
    y[n] = fmaxf(s + bias[n], 0.f);
  }
}

// ---------------------------------------------------------------------------
// cdist: d[b][i][j] = || esrow(b,i) - etrow(b,j) ||_2
// ---------------------------------------------------------------------------
__global__ __launch_bounds__(256) void cdist_kernel(
    const float* __restrict__ es, const float* __restrict__ et,
    const float* __restrict__ ev, float* __restrict__ d) {
  const int b = blockIdx.z;
  const int i0 = blockIdx.x * 32;
  const int j0 = blockIdx.y * 32;
  __shared__ float sA[32][33];
  __shared__ float sB[32][33];
  const int tid = threadIdx.x;
  const int ty = tid / 16, tx = tid % 16;
  const int lr = tid / 8;
  const int lk4 = (tid % 8) * 4;
  const int gi = i0 + lr;
  const int gj = j0 + lr;
  const float* pa = (gi < NNODE) ? (es + ((size_t)b * NNODE + gi) * DIM) : ev;
  const float* pb = (gj < NNODE) ? (et + ((size_t)b * NNODE + gj) * DIM) : ev;
  float acc[2][2] = {};
  for (int k0 = 0; k0 < DIM; k0 += 32) {
    float4 av = *(const float4*)(pa + k0 + lk4);
    float4 bv = *(const float4*)(pb + k0 + lk4);
    sA[lr][lk4 + 0] = av.x; sA[lr][lk4 + 1] = av.y;
    sA[lr][lk4 + 2] = av.z; sA[lr][lk4 + 3] = av.w;
    sB[lr][lk4 + 0] = bv.x; sB[lr][lk4 + 1] = bv.y;
    sB[lr][lk4 + 2] = bv.z; sB[lr][lk4 + 3] = bv.w;
    __syncthreads();
#pragma unroll 8
    for (int k = 0; k < 32; ++k) {
      float a0 = sA[ty * 2 + 0][k], a1 = sA[ty * 2 + 1][k];
      float b0 = sB[tx * 2 + 0][k], b1 = sB[tx * 2 + 1][k];
      float d00 = a0 - b0, d01 = a0 - b1, d10 = a1 - b0, d11 = a1 - b1;
      acc[0][0] = fmaf(d00, d00, acc[0][0]);
      acc[0][1] = fmaf(d01, d01, acc[0][1]);
      acc[1][0] = fmaf(d10, d10, acc[1][0]);
      acc[1][1] = fmaf(d11, d11, acc[1][1]);
    }
    __syncthreads();
  }
#pragma unroll
  for (int i = 0; i < 2; ++i) {
    int gi2 = i0 + ty * 2 + i;
#pragma unroll
    for (int j = 0; j < 2; ++j) {
      int gj2 = j0 + tx * 2 + j;
      if (gi2 < NP1 && gj2 < NP1)
        d[(size_t)b * EDSZ + gi2 * NP1 + gj2] = sqrtf(acc[i][j]);
    }
  }
}

// ---------------------------------------------------------------------------
// Deterministic per-batch sum (fp64 tree)
// ---------------------------------------------------------------------------
__global__ __launch_bounds__(256) void batch_sum(
    const float* __restrict__ d, float* __restrict__ sums) {
  const int b = blockIdx.x;
  double s = 0.0;
  for (int idx = threadIdx.x; idx < EDSZ; idx += 256)
    s += (double)d[(size_t)b * EDSZ + idx];
  __shared__ double red[256];
  red[threadIdx.x] = s;
  __syncthreads();
  for (int off = 128; off; off >>= 1) {
    if (threadIdx.x < off) red[threadIdx.x] += red[threadIdx.x + off];
    __syncthreads();
  }
  if (threadIdx.x == 0) sums[b] = (float)red[0];
}

// ---------------------------------------------------------------------------
// normalize: edit = d / sum[b] * N*N
// ---------------------------------------------------------------------------
__global__ __launch_bounds__(256) void normalize_kernel(
    const float* __restrict__ d, const float* __restrict__ sums,
    float* __restrict__ edit) {
  int idx = blockIdx.x * 256 + threadIdx.x;
  if (idx < BATCH * EDSZ) {
    int b = idx / EDSZ;
    edit[idx] = d[idx] / sums[b] * (float)(NNODE * NNODE);
  }
}

// ---------------------------------------------------------------------------
// cross-lane helpers: VALU-pipe (DPP / readlane)
// ---------------------------------------------------------------------------
// Packed (value,col): hi32 = f32 bits of nonneg value, lo32 = column id.
// v_min_f64 on this packing = min by value, ties -> lowest column.
__device__ __forceinline__ double pack_mc(float m, unsigned col) {
  union { double d; unsigned u[2]; } r;
  r.u[0] = col;
  r.u[1] = __float_as_uint(m);
  return r.d;
}

template <int CTRL>
__device__ __forceinline__ double dpp_min_step_pk(double x) {
  union { double d; unsigned long long q; int i[2]; } s, o, r;
  s.d = x;
  o.q = 0x7FEFFFFFFFFFFFFFULL;  // max finite double: identity for packed min
  r.i[0] = __builtin_amdgcn_update_dpp(o.i[0], s.i[0], CTRL, 0xf, 0xf, false);
  r.i[1] = __builtin_amdgcn_update_dpp(o.i[1], s.i[1], CTRL, 0xf, 0xf, false);
  return fmin(x, r.d);
}

// wave64 packed argmin: returns (delta, col) of the global min, uniform.
__device__ __forceinline__ void wave_argmin_pk(double x, float& delta, int& col) {
  x = dpp_min_step_pk<0x111>(x);  // row_shr:1
  x = dpp_min_step_pk<0x112>(x);  // row_shr:2
  x = dpp_min_step_pk<0x114>(x);  // row_shr:4
  x = dpp_min_step_pk<0x118>(x);  // row_shr:8
  x = dpp_min_step_pk<0x142>(x);  // row_bcast:15
  x = dpp_min_step_pk<0x143>(x);  // row_bcast:31
  union { double d; int i[2]; } s;
  s.d = x;
  col = __builtin_amdgcn_readlane(s.i[0], 63);
  delta = __uint_as_float((unsigned)__builtin_amdgcn_readlane(s.i[1], 63));
}

__device__ __forceinline__ float fsel2(float a0, float a1, int s) {
  return (s == 0) ? a0 : a1;
}
__device__ __forceinline__ int isel2(int a0, int a1, int s) {
  return (s == 0) ? a0 : a1;
}

// ---------------------------------------------------------------------------
// LSAPE collapsed to a dense 128x128 LSAP:
//   D[i][j] = min( ec[i][j], ec[i][128] + ec[128][j] )   (>= 0, finite)
// A perfect matching on D has the same optimal cost as the reference's
// 256x256 LSAP; per matched pair, re-comparing the two branches recovers
// the reference A exactly (substitution if ec[i][j] < del+ins, else
// delete+insert; virtual-virtual pairs collapse into A[128][128] := 0).
// ONE WAVE per batch, lane owns 2 columns, SSP with zero-dual init
// (round-4 structure, our fastest), VALU-pipe cross-lane ops only.
// ---------------------------------------------------------------------------
__global__ __launch_bounds__(64) void lsap_kernel(
    const float* __restrict__ edit, float* __restrict__ Aout,
    float* __restrict__ geds) {
  const int b = blockIdx.x;
  const float* ec = edit + (size_t)b * EDSZ;
  float* A = Aout + (size_t)b * EDSZ;
  const int lane = threadIdx.x;
  const int cbase = lane * 2;  // first owned column (0-based), 2 per lane

  __shared__ float D[NNODE * NNODE];  // 64 KB dense collapsed cost

  // stage D = min(sub, del+ins); coalesced global reads (L2-resident)
  for (int idx = lane; idx < NNODE * NNODE; idx += 64) {
    const int i = idx >> 7, j = idx & 127;
    const float sub = ec[i * NP1 + j];
    const float di = ec[i * NP1 + NNODE] + ec[NNODE * NP1 + j];
    D[idx] = fminf(sub, di);
  }
  for (int idx = lane; idx < EDSZ; idx += 64) A[idx] = 0.f;
  __syncthreads();

  // per-lane state: 2 columns (v, minv, way, p) + 2 rows (u)
  float u0 = 0.f, u1 = 0.f;
  float v0 = 0.f, v1 = 0.f;
  float m0, m1;
  int w0 = 0, w1 = 0;
  int p0 = 0, p1 = 0;

  for (int i = 1; i <= NNODE; ++i) {
    unsigned cused = 0, rused = 0;
    m0 = m1 = BIGF;
    int j0 = 0;       // current column (0 = dummy start)
    int i0 = i;       // p[0] = i
    for (int guard = 0; guard <= NNODE; ++guard) {
      // --- mark used: column j0 (skip dummy col 0) and its row i0 ---
      if (j0 > 0 && lane == ((j0 - 1) >> 1)) {
        if (((j0 - 1) & 1) == 0) { cused |= 1u; m0 = BIGF; }
        else { cused |= 2u; m1 = BIGF; }
      }
      if (lane == ((i0 - 1) >> 1)) rused |= 1u << ((i0 - 1) & 1);

      // --- broadcast u[i0] from owning lane (i0 uniform -> readlane) ---
      const float u_i0 = __uint_as_float((unsigned)__builtin_amdgcn_readlane(
          (int)__float_as_uint(fsel2(u0, u1, (i0 - 1) & 1)), (i0 - 1) >> 1));

      // --- dense cost row: one float2 per lane, no special cases ---
      const float2 f = *(const float2*)&D[(i0 - 1) * NNODE + cbase];

      // --- relax free columns; clamp >=0 keeps packed ordering sound ---
      const bool f0 = !(cused & 1u), f1 = !(cused & 2u);
      {
        float cur = fmaxf(f.x - u_i0 - v0, 0.f);
        bool up = f0 && (cur < m0);
        m0 = up ? cur : m0; w0 = up ? j0 : w0;
      }
      {
        float cur = fmaxf(f.y - u_i0 - v1, 0.f);
        bool up = f1 && (cur < m1);
        m1 = up ? cur : m1; w1 = up ? j0 : w1;
      }

      // --- packed local min (ties -> lowest col), then wave argmin ---
      const double loc = fmin(pack_mc(m0, cbase + 0), pack_mc(m1, cbase + 1));
      float delta; int jcol;
      wave_argmin_pk(loc, delta, jcol);
      const int j1 = jcol + 1;

      // --- dual updates (registers only) ---
      if (!f0) v0 -= delta; else m0 = fmaxf(m0 - delta, 0.f);
      if (!f1) v1 -= delta; else m1 = fmaxf(m1 - delta, 0.f);
      if (rused & 1u) u0 += delta;
      if (rused & 2u) u1 += delta;

      // --- next (or break on free column) ---
      const int pj1 = __builtin_amdgcn_readlane(
          isel2(p0, p1, (j1 - 1) & 1), (j1 - 1) >> 1);
      j0 = j1;
      if (pj1 == 0) break;
      i0 = pj1;
    }

    // --- augment along way[] chain (uniform walk via readlane) ---
    int jc = j0;
    while (jc != 0) {
      const int cl = (jc - 1) >> 1, cq = (jc - 1) & 1;
      const int jp = __builtin_amdgcn_readlane(isel2(w0, w1, cq), cl);
      const int js = (jp == 0) ? 1 : jp;  // safe index for speculative readlane
      const int pvr = __builtin_amdgcn_readlane(
          isel2(p0, p1, (js - 1) & 1), (js - 1) >> 1);
      const int pv = (jp == 0) ? i : pvr;
      if (lane == cl) {
        if (cq == 0) p0 = pv;
        else p1 = pv;
      }
      jc = jp;
    }
  }

  // --- emit A and geds: column j assigned row p[j+1]-1; re-split branches ---
  double contrib = 0.0;
  {
    const int pr[2] = {p0, p1};
#pragma unroll
    for (int q = 0; q < 2; ++q) {
      const int j = cbase + q;
      const int i = pr[q] - 1;
      const float sub = ec[i * NP1 + j];
      const float di = ec[i * NP1 + NNODE] + ec[NNODE * NP1 + j];
      if (sub < di) {
        A[i * NP1 + j] = 1.f;
        contrib += (double)sub;
      } else {
        A[i * NP1 + NNODE] = 1.f;    // delete row i
        A[NNODE * NP1 + j] = 1.f;    // insert col j
        contrib += (double)di;
      }
    }
  }
#pragma unroll
  for (int off = 32; off; off >>= 1) contrib += __shfl_xor(contrib, off);
  if (lane == 0) geds[b] = (float)(contrib / 256.0);
}

// ---------------------------------------------------------------------------
// launch
// ---------------------------------------------------------------------------
extern "C" void kernel_launch(void* const* d_in, const int* in_sizes, int n_in,
                              void* d_out, int out_size, void* d_ws, size_t ws_size,
                              hipStream_t stream) {
  const float* x_s  = (const float*)d_in[0];
  const float* x_t  = (const float*)d_in[1];
  const float* W1   = (const float*)d_in[2];
  const float* b1   = (const float*)d_in[3];
  const float* W2   = (const float*)d_in[4];
  const float* b2   = (const float*)d_in[5];
  const float* virt = (const float*)d_in[6];

  const int M = BATCH * NNODE;  // 2048

  float* ws    = (float*)d_ws;
  float* h_s   = ws;
  float* h_t   = h_s + (size_t)M * DIM;
  float* e_s   = h_t + (size_t)M * DIM;
  float* e_t   = e_s + (size_t)M * DIM;
  float* h_v   = e_t + (size_t)M * DIM;
  float* e_v   = h_v + DIM;
  float* d_raw = e_v + DIM;
  float* sums  = d_raw + (size_t)BATCH * EDSZ;

  float* Aout = (float*)d_out;
  float* edit = Aout + (size_t)BATCH * EDSZ;
  float* geds = edit + (size_t)BATCH * EDSZ;

  dim3 gblk(M / 64, DIM / 64);
  gemm_nt_relu<<<gblk, 256, 0, stream>>>(x_s, W1, b1, h_s, M, DIM, DIM);
  gemm_nt_relu<<<gblk, 256, 0, stream>>>(x_t, W1, b1, h_t, M, DIM, DIM);
  vec_gemm_relu<<<1, 256, 0, stream>>>(virt, W1, b1, h_v);
  gemm_nt_relu<<<gblk, 256, 0, stream>>>(h_s, W2, b2, e_s, M, DIM, DIM);
  gemm_nt_relu<<<gblk, 256, 0, stream>>>(h_t, W2, b2, e_t, M, DIM, DIM);
  vec_gemm_relu<<<1, 256, 0, stream>>>(h_v, W2, b2, e_v);

  cdist_kernel<<<dim3(5, 5, BATCH), 256, 0, stream>>>(e_s, e_t, e_v, d_raw);
  batch_sum<<<BATCH, 256, 0, stream>>>(d_raw, sums);
  normalize_kernel<<<(BATCH * EDSZ + 255) / 256, 256, 0, stream>>>(d_raw, sums, edit);
  lsap_kernel<<<BATCH, 64, 0, stream>>>(edit, Aout, geds);
}

// Round 7
// 972.434 us; speedup vs baseline: 12.8172x; 1.3857x over previous
//
#include <hip/hip_runtime.h>

// ---------------------------------------------------------------------------
// Problem constants (B=16, N=128, FIN=D=512)
// ---------------------------------------------------------------------------
#define BATCH 16
#define NNODE 128
#define DIM 512
#define NP1 129              // N+1 (with virtual node)
#define EDSZ (NP1 * NP1)     // 16641 per batch
#define BIGF 3.0e38f         // sentinel (finite, packable)

// ---------------------------------------------------------------------------
// GEMM (NT): Y[m][n] = relu( sum_k A[m][k] * W[n][k] + bias[n] )
// ---------------------------------------------------------------------------
__global__ __launch_bounds__(256) void gemm_nt_relu(
    const float* __restrict__ A, const float* __restrict__ W,
    const float* __restrict__ bias, float* __restrict__ Y,
    int M, int N, int K) {
  __shared__ float sA[16][65];
  __shared__ float sB[16][65];
  const int tid = threadIdx.x;
  const int m0 = blockIdx.x * 64;
  const int n0 = blockIdx.y * 64;
  const int tm = tid / 16, tn = tid % 16;
  const int lr = tid / 4;
  const int lk = (tid % 4) * 4;
  float acc[4][4] = {};
  for (int k0 = 0; k0 < K; k0 += 16) {
    float4 av = *(const float4*)(A + (size_t)(m0 + lr) * K + k0 + lk);
    float4 wv = *(const float4*)(W + (size_t)(n0 + lr) * K + k0 + lk);
    sA[lk + 0][lr] = av.x; sA[lk + 1][lr] = av.y;
    sA[lk + 2][lr] = av.z; sA[lk + 3][lr] = av.w;
    sB[lk + 0][lr] = wv.x; sB[lk + 1][lr] = wv.y;
    sB[lk + 2][lr] = wv.z; sB[lk + 3][lr] = wv.w;
    __syncthreads();
#pragma unroll
    for (int k = 0; k < 16; ++k) {
      float a[4], b[4];
#pragma unroll
      for (int q = 0; q < 4; ++q) { a[q] = sA[k][tm * 4 + q]; b[q] = sB[k][tn * 4 + q]; }
#pragma unroll
      for (int i = 0; i < 4; ++i)
#pragma unroll
        for (int j = 0; j < 4; ++j) acc[i][j] = fmaf(a[i], b[j], acc[i][j]);
    }
    __syncthreads();
  }
#pragma unroll
  for (int i = 0; i < 4; ++i) {
    int m = m0 + tm * 4 + i;
#pragma unroll
    for (int j = 0; j < 4; ++j) {
      int n = n0 + tn * 4 + j;
      Y[(size_t)m * N + n] = fmaxf(acc[i][j] + bias[n], 0.f);
    }
  }
}

// ---------------------------------------------------------------------------
// Single-row embed (virtual node)
// ---------------------------------------------------------------------------
__global__ __launch_bounds__(256) void vec_gemm_relu(
    const float* __restrict__ x, const float* __restrict__ W,
    const float* __restrict__ bias, float* __restrict__ y) {
  __shared__ float sx[DIM];
  for (int k = threadIdx.x; k < DIM; k += 256) sx[k] = x[k];
  __syncthreads();
  for (int n = threadIdx.x; n < DIM; n += 256) {
    const float* w = W + (size_t)n * DIM;
    float s = 0.f;
    for (int k = 0; k < DIM; k += 4) {
      float4 wv = *(const float4*)(w + k);
      s = fmaf(sx[k + 0], wv.x, s);
      s = fmaf(sx[k + 1], wv.y, s);
      s = fmaf(sx[k + 2], wv.z, s);
      s = fmaf(sx[k + 3], wv.w, s);
    }
    y[n] = fmaxf(s + bias[n], 0.f);
  }
}

// ---------------------------------------------------------------------------
// cdist: d[b][i][j] = || esrow(b,i) - etrow(b,j) ||_2
// ---------------------------------------------------------------------------
__global__ __launch_bounds__(256) void cdist_kernel(
    const float* __restrict__ es, const float* __restrict__ et,
    const float* __restrict__ ev, float* __restrict__ d) {
  const int b = blockIdx.z;
  const int i0 = blockIdx.x * 32;
  const int j0 = blockIdx.y * 32;
  __shared__ float sA[32][33];
  __shared__ float sB[32][33];
  const int tid = threadIdx.x;
  const int ty = tid / 16, tx = tid % 16;
  const int lr = tid / 8;
  const int lk4 = (tid % 8) * 4;
  const int gi = i0 + lr;
  const int gj = j0 + lr;
  const float* pa = (gi < NNODE) ? (es + ((size_t)b * NNODE + gi) * DIM) : ev;
  const float* pb = (gj < NNODE) ? (et + ((size_t)b * NNODE + gj) * DIM) : ev;
  float acc[2][2] = {};
  for (int k0 = 0; k0 < DIM; k0 += 32) {
    float4 av = *(const float4*)(pa + k0 + lk4);
    float4 bv = *(const float4*)(pb + k0 + lk4);
    sA[lr][lk4 + 0] = av.x; sA[lr][lk4 + 1] = av.y;
    sA[lr][lk4 + 2] = av.z; sA[lr][lk4 + 3] = av.w;
    sB[lr][lk4 + 0] = bv.x; sB[lr][lk4 + 1] = bv.y;
    sB[lr][lk4 + 2] = bv.z; sB[lr][lk4 + 3] = bv.w;
    __syncthreads();
#pragma unroll 8
    for (int k = 0; k < 32; ++k) {
      float a0 = sA[ty * 2 + 0][k], a1 = sA[ty * 2 + 1][k];
      float b0 = sB[tx * 2 + 0][k], b1 = sB[tx * 2 + 1][k];
      float d00 = a0 - b0, d01 = a0 - b1, d10 = a1 - b0, d11 = a1 - b1;
      acc[0][0] = fmaf(d00, d00, acc[0][0]);
      acc[0][1] = fmaf(d01, d01, acc[0][1]);
      acc[1][0] = fmaf(d10, d10, acc[1][0]);
      acc[1][1] = fmaf(d11, d11, acc[1][1]);
    }
    __syncthreads();
  }
#pragma unroll
  for (int i = 0; i < 2; ++i) {
    int gi2 = i0 + ty * 2 + i;
#pragma unroll
    for (int j = 0; j < 2; ++j) {
      int gj2 = j0 + tx * 2 + j;
      if (gi2 < NP1 && gj2 < NP1)
        d[(size_t)b * EDSZ + gi2 * NP1 + gj2] = sqrtf(acc[i][j]);
    }
  }
}

// ---------------------------------------------------------------------------
// Deterministic per-batch sum (fp64 tree)
// ---------------------------------------------------------------------------
__global__ __launch_bounds__(256) void batch_sum(
    const float* __restrict__ d, float* __restrict__ sums) {
  const int b = blockIdx.x;
  double s = 0.0;
  for (int idx = threadIdx.x; idx < EDSZ; idx += 256)
    s += (double)d[(size_t)b * EDSZ + idx];
  __shared__ double red[256];
  red[threadIdx.x] = s;
  __syncthreads();
  for (int off = 128; off; off >>= 1) {
    if (threadIdx.x < off) red[threadIdx.x] += red[threadIdx.x + off];
    __syncthreads();
  }
  if (threadIdx.x == 0) sums[b] = (float)red[0];
}

// ---------------------------------------------------------------------------
// normalize: edit = d / sum[b] * N*N
// ---------------------------------------------------------------------------
__global__ __launch_bounds__(256) void normalize_kernel(
    const float* __restrict__ d, const float* __restrict__ sums,
    float* __restrict__ edit) {
  int idx = blockIdx.x * 256 + threadIdx.x;
  if (idx < BATCH * EDSZ) {
    int b = idx / EDSZ;
    edit[idx] = d[idx] / sums[b] * (float)(NNODE * NNODE);
  }
}

// ---------------------------------------------------------------------------
// cross-lane helpers: VALU-pipe (DPP / readlane)
// ---------------------------------------------------------------------------
// Packed (value,col): hi32 = f32 bits of nonneg value, lo32 = column id.
// v_min_f64 on this packing = min by value, ties -> lowest column.
__device__ __forceinline__ double pack_mc(float m, unsigned col) {
  union { double d; unsigned u[2]; } r;
  r.u[0] = col;
  r.u[1] = __float_as_uint(m);
  return r.d;
}

template <int CTRL>
__device__ __forceinline__ double dpp_min_step_pk(double x) {
  union { double d; unsigned long long q; int i[2]; } s, o, r;
  s.d = x;
  o.q = 0x7FEFFFFFFFFFFFFFULL;  // max finite double: identity for packed min
  r.i[0] = __builtin_amdgcn_update_dpp(o.i[0], s.i[0], CTRL, 0xf, 0xf, false);
  r.i[1] = __builtin_amdgcn_update_dpp(o.i[1], s.i[1], CTRL, 0xf, 0xf, false);
  return fmin(x, r.d);
}

// wave64 packed argmin: returns (delta, col) of the global min, uniform.
__device__ __forceinline__ void wave_argmin_pk(double x, float& delta, int& col) {
  x = dpp_min_step_pk<0x111>(x);  // row_shr:1
  x = dpp_min_step_pk<0x112>(x);  // row_shr:2
  x = dpp_min_step_pk<0x114>(x);  // row_shr:4
  x = dpp_min_step_pk<0x118>(x);  // row_shr:8
  x = dpp_min_step_pk<0x142>(x);  // row_bcast:15
  x = dpp_min_step_pk<0x143>(x);  // row_bcast:31
  union { double d; int i[2]; } s;
  s.d = x;
  col = __builtin_amdgcn_readlane(s.i[0], 63);
  delta = __uint_as_float((unsigned)__builtin_amdgcn_readlane(s.i[1], 63));
}

__device__ __forceinline__ float fsel2(float a0, float a1, int s) {
  return (s == 0) ? a0 : a1;
}
__device__ __forceinline__ int isel2(int a0, int a1, int s) {
  return (s == 0) ? a0 : a1;
}

// ---------------------------------------------------------------------------
// LSAPE collapsed to a dense 128x128 LSAP:
//   D[i][j] = min( ec[i][j], ec[i][128] + ec[128][j] )   (>= 0, finite)
// then LAPJV-style column reduction (valid dual init + conflict-free greedy
// partial assignment) + shortest-augmenting-path for the remaining free rows.
// ONE WAVE per batch, lane owns 2 columns, VALU-pipe cross-lane ops only.
// Exactness: column reduction preserves reduced-costs >= 0 and complementary
// slackness; SSP completes an exact optimum; per matched pair, re-comparing
// sub vs del+ins recovers the reference A (optimum unique within fp margin).
// ---------------------------------------------------------------------------
__global__ __launch_bounds__(64) void lsap_kernel(
    const float* __restrict__ edit, float* __restrict__ Aout,
    float* __restrict__ geds) {
  const int b = blockIdx.x;
  const float* ec = edit + (size_t)b * EDSZ;
  float* A = Aout + (size_t)b * EDSZ;
  const int lane = threadIdx.x;
  const int cbase = lane * 2;  // first owned column (0-based), 2 per lane

  __shared__ float D[NNODE * NNODE];  // 64 KB dense collapsed cost

  // stage D = min(sub, del+ins); coalesced global reads (L2-resident)
  for (int idx = lane; idx < NNODE * NNODE; idx += 64) {
    const int i = idx >> 7, j = idx & 127;
    const float sub = ec[i * NP1 + j];
    const float di = ec[i * NP1 + NNODE] + ec[NNODE * NP1 + j];
    D[idx] = fminf(sub, di);
  }
  for (int idx = lane; idx < EDSZ; idx += 64) A[idx] = 0.f;
  __syncthreads();

  // per-lane state: 2 columns (v, minv, way, p) + 2 rows (u)
  float u0 = 0.f, u1 = 0.f;
  float v0 = 0.f, v1 = 0.f;
  float m0, m1;
  int w0 = 0, w1 = 0;
  int p0 = 0, p1 = 0;

  // ---------------- Phase 1: column reduction on dense D ----------------
  // v[j] = min_i D[i][j], y[j] = argmin row (lowest on tie). Independent
  // loads pipeline; 2 columns per lane.
  int y0 = 0, y1 = 0;
  {
    float c0 = BIGF, c1 = BIGF;
    for (int r = 0; r < NNODE; ++r) {
      const float2 f = *(const float2*)&D[r * NNODE + cbase];
      if (f.x < c0) { c0 = f.x; y0 = r; }
      if (f.y < c1) { c1 = f.y; y1 = r; }
    }
    v0 = c0; v1 = c1;
  }

  // Greedy conflict-free assignment (wave-uniform scalar walk over columns).
  unsigned long long ra0 = 0, ra1 = 0;  // assigned-row bits (0..63, 64..127)
  for (int j = 0; j < NNODE; ++j) {
    const int jl = j >> 1, jq = j & 1;
    const int i1 = __builtin_amdgcn_readlane(isel2(y0, y1, jq), jl);
    const int bit = i1 & 63;
    const unsigned long long msk = (i1 < 64) ? ra0 : ra1;
    if (!((msk >> bit) & 1ull)) {
      if (i1 < 64) ra0 |= 1ull << bit; else ra1 |= 1ull << bit;
      if (lane == jl) {
        if (jq == 0) p0 = i1 + 1;
        else p1 = i1 + 1;
      }
    }
  }

  // ---------------- Phase 2: SAP for each free row ----------------
  for (int ii = 0; ii < NNODE; ++ii) {
    const unsigned long long amsk = (ii < 64) ? ra0 : ra1;
    if ((amsk >> (ii & 63)) & 1ull) continue;  // assigned in phase 1
    const int i = ii + 1;

    unsigned cused = 0, rused = 0;
    m0 = m1 = BIGF;
    int j0 = 0;       // current column (0 = dummy start)
    int i0 = i;       // p[0] = i
    for (int guard = 0; guard <= NNODE; ++guard) {
      // --- mark used: column j0 (skip dummy col 0) and its row i0 ---
      if (j0 > 0 && lane == ((j0 - 1) >> 1)) {
        if (((j0 - 1) & 1) == 0) { cused |= 1u; m0 = BIGF; }
        else { cused |= 2u; m1 = BIGF; }
      }
      if (lane == ((i0 - 1) >> 1)) rused |= 1u << ((i0 - 1) & 1);

      // --- broadcast u[i0] from owning lane (i0 uniform -> readlane) ---
      const float u_i0 = __uint_as_float((unsigned)__builtin_amdgcn_readlane(
          (int)__float_as_uint(fsel2(u0, u1, (i0 - 1) & 1)), (i0 - 1) >> 1));

      // --- dense cost row: one float2 per lane, no special cases ---
      const float2 f = *(const float2*)&D[(i0 - 1) * NNODE + cbase];

      // --- relax free columns; clamp >=0 keeps packed ordering sound ---
      const bool f0 = !(cused & 1u), f1 = !(cused & 2u);
      {
        float cur = fmaxf(f.x - u_i0 - v0, 0.f);
        bool up = f0 && (cur < m0);
        m0 = up ? cur : m0; w0 = up ? j0 : w0;
      }
      {
        float cur = fmaxf(f.y - u_i0 - v1, 0.f);
        bool up = f1 && (cur < m1);
        m1 = up ? cur : m1; w1 = up ? j0 : w1;
      }

      // --- packed local min (ties -> lowest col), then wave argmin ---
      const double loc = fmin(pack_mc(m0, cbase + 0), pack_mc(m1, cbase + 1));
      float delta; int jcol;
      wave_argmin_pk(loc, delta, jcol);
      const int j1 = jcol + 1;

      // --- dual updates (registers only) ---
      if (!f0) v0 -= delta; else m0 = fmaxf(m0 - delta, 0.f);
      if (!f1) v1 -= delta; else m1 = fmaxf(m1 - delta, 0.f);
      if (rused & 1u) u0 += delta;
      if (rused & 2u) u1 += delta;

      // --- next (or break on free column) ---
      const int pj1 = __builtin_amdgcn_readlane(
          isel2(p0, p1, (j1 - 1) & 1), (j1 - 1) >> 1);
      j0 = j1;
      if (pj1 == 0) break;
      i0 = pj1;
    }

    // --- augment along way[] chain (uniform walk via readlane) ---
    int jc = j0;
    while (jc != 0) {
      const int cl = (jc - 1) >> 1, cq = (jc - 1) & 1;
      const int jp = __builtin_amdgcn_readlane(isel2(w0, w1, cq), cl);
      const int js = (jp == 0) ? 1 : jp;  // safe index for speculative readlane
      const int pvr = __builtin_amdgcn_readlane(
          isel2(p0, p1, (js - 1) & 1), (js - 1) >> 1);
      const int pv = (jp == 0) ? i : pvr;
      if (lane == cl) {
        if (cq == 0) p0 = pv;
        else p1 = pv;
      }
      jc = jp;
    }
  }

  // --- emit A and geds: column j assigned row p[j+1]-1; re-split branches ---
  double contrib = 0.0;
  {
    const int pr[2] = {p0, p1};
#pragma unroll
    for (int q = 0; q < 2; ++q) {
      const int j = cbase + q;
      const int i = pr[q] - 1;
      const float sub = ec[i * NP1 + j];
      const float di = ec[i * NP1 + NNODE] + ec[NNODE * NP1 + j];
      if (sub < di) {
        A[i * NP1 + j] = 1.f;
        contrib += (double)sub;
      } else {
        A[i * NP1 + NNODE] = 1.f;    // delete row i
        A[NNODE * NP1 + j] = 1.f;    // insert col j
        contrib += (double)di;
      }
    }
  }
#pragma unroll
  for (int off = 32; off; off >>= 1) contrib += __shfl_xor(contrib, off);
  if (lane == 0) geds[b] = (float)(contrib / 256.0);
}

// ---------------------------------------------------------------------------
// launch
// ---------------------------------------------------------------------------
extern "C" void kernel_launch(void* const* d_in, const int* in_sizes, int n_in,
                              void* d_out, int out_size, void* d_ws, size_t ws_size,
                              hipStream_t stream) {
  const float* x_s  = (const float*)d_in[0];
  const float* x_t  = (const float*)d_in[1];
  const float* W1   = (const float*)d_in[2];
  const float* b1   = (const float*)d_in[3];
  const float* W2   = (const float*)d_in[4];
  const float* b2   = (const float*)d_in[5];
  const float* virt = (const float*)d_in[6];

  const int M = BATCH * NNODE;  // 2048

  float* ws    = (float*)d_ws;
  float* h_s   = ws;
  float* h_t   = h_s + (size_t)M * DIM;
  float* e_s   = h_t + (size_t)M * DIM;
  float* e_t   = e_s + (size_t)M * DIM;
  float* h_v   = e_t + (size_t)M * DIM;
  float* e_v   = h_v + DIM;
  float* d_raw = e_v + DIM;
  float* sums  = d_raw + (size_t)BATCH * EDSZ;

  float* Aout = (float*)d_out;
  float* edit = Aout + (size_t)BATCH * EDSZ;
  float* geds = edit + (size_t)BATCH * EDSZ;

  dim3 gblk(M / 64, DIM / 64);
  gemm_nt_relu<<<gblk, 256, 0, stream>>>(x_s, W1, b1, h_s, M, DIM, DIM);
  gemm_nt_relu<<<gblk, 256, 0, stream>>>(x_t, W1, b1, h_t, M, DIM, DIM);
  vec_gemm_relu<<<1, 256, 0, stream>>>(virt, W1, b1, h_v);
  gemm_nt_relu<<<gblk, 256, 0, stream>>>(h_s, W2, b2, e_s, M, DIM, DIM);
  gemm_nt_relu<<<gblk, 256, 0, stream>>>(h_t, W2, b2, e_t, M, DIM, DIM);
  vec_gemm_relu<<<1, 256, 0, stream>>>(h_v, W2, b2, e_v);

  cdist_kernel<<<dim3(5, 5, BATCH), 256, 0, stream>>>(e_s, e_t, e_v, d_raw);
  batch_sum<<<BATCH, 256, 0, stream>>>(d_raw, sums);
  normalize_kernel<<<(BATCH * EDSZ + 255) / 256, 256, 0, stream>>>(d_raw, sums, edit);
  lsap_kernel<<<BATCH, 64, 0, stream>>>(edit, Aout, geds);
}

// Round 8
// 936.326 us; speedup vs baseline: 13.3115x; 1.0386x over previous
//
#include <hip/hip_runtime.h>

// ---------------------------------------------------------------------------
// Problem constants (B=16, N=128, FIN=D=512)
// ---------------------------------------------------------------------------
#define BATCH 16
#define NNODE 128
#define DIM 512
#define NP1 129              // N+1 (with virtual node)
#define EDSZ (NP1 * NP1)     // 16641 per batch
#define BIGF 3.0e38f         // sentinel (finite, packable)

// ---------------------------------------------------------------------------
// GEMM (NT): Y[m][n] = relu( sum_k A[m][k] * W[n][k] + bias[n] )
// ---------------------------------------------------------------------------
__global__ __launch_bounds__(256) void gemm_nt_relu(
    const float* __restrict__ A, const float* __restrict__ W,
    const float* __restrict__ bias, float* __restrict__ Y,
    int M, int N, int K) {
  __shared__ float sA[16][65];
  __shared__ float sB[16][65];
  const int tid = threadIdx.x;
  const int m0 = blockIdx.x * 64;
  const int n0 = blockIdx.y * 64;
  const int tm = tid / 16, tn = tid % 16;
  const int lr = tid / 4;
  const int lk = (tid % 4) * 4;
  float acc[4][4] = {};
  for (int k0 = 0; k0 < K; k0 += 16) {
    float4 av = *(const float4*)(A + (size_t)(m0 + lr) * K + k0 + lk);
    float4 wv = *(const float4*)(W + (size_t)(n0 + lr) * K + k0 + lk);
    sA[lk + 0][lr] = av.x; sA[lk + 1][lr] = av.y;
    sA[lk + 2][lr] = av.z; sA[lk + 3][lr] = av.w;
    sB[lk + 0][lr] = wv.x; sB[lk + 1][lr] = wv.y;
    sB[lk + 2][lr] = wv.z; sB[lk + 3][lr] = wv.w;
    __syncthreads();
#pragma unroll
    for (int k = 0; k < 16; ++k) {
      float a[4], b[4];
#pragma unroll
      for (int q = 0; q < 4; ++q) { a[q] = sA[k][tm * 4 + q]; b[q] = sB[k][tn * 4 + q]; }
#pragma unroll
      for (int i = 0; i < 4; ++i)
#pragma unroll
        for (int j = 0; j < 4; ++j) acc[i][j] = fmaf(a[i], b[j], acc[i][j]);
    }
    __syncthreads();
  }
#pragma unroll
  for (int i = 0; i < 4; ++i) {
    int m = m0 + tm * 4 + i;
#pragma unroll
    for (int j = 0; j < 4; ++j) {
      int n = n0 + tn * 4 + j;
      Y[(size_t)m * N + n] = fmaxf(acc[i][j] + bias[n], 0.f);
    }
  }
}

// ---------------------------------------------------------------------------
// Single-row embed (virtual node)
// ---------------------------------------------------------------------------
__global__ __launch_bounds__(256) void vec_gemm_relu(
    const float* __restrict__ x, const float* __restrict__ W,
    const float* __restrict__ bias, float* __restrict__ y) {
  __shared__ float sx[DIM];
  for (int k = threadIdx.x; k < DIM; k += 256) sx[k] = x[k];
  __syncthreads();
  for (int n = threadIdx.x; n < DIM; n += 256) {
    const float* w = W + (size_t)n * DIM;
    float s = 0.f;
    for (int k = 0; k < DIM; k += 4) {
      float4 wv = *(const float4*)(w + k);
      s = fmaf(sx[k + 0], wv.x, s);
      s = fmaf(sx[k + 1], wv.y, s);
      s = fmaf(sx[k + 2], wv.z, s);
      s = fmaf(sx[k + 3], wv.w, s);
    }
    y[n] = fmaxf(s + bias[n], 0.f);
  }
}

// ---------------------------------------------------------------------------
// cdist: d[b][i][j] = || esrow(b,i) - etrow(b,j) ||_2
// ---------------------------------------------------------------------------
__global__ __launch_bounds__(256) void cdist_kernel(
    const float* __restrict__ es, const float* __restrict__ et,
    const float* __restrict__ ev, float* __restrict__ d) {
  const int b = blockIdx.z;
  const int i0 = blockIdx.x * 32;
  const int j0 = blockIdx.y * 32;
  __shared__ float sA[32][33];
  __shared__ float sB[32][33];
  const int tid = threadIdx.x;
  const int ty = tid / 16, tx = tid % 16;
  const int lr = tid / 8;
  const int lk4 = (tid % 8) * 4;
  const int gi = i0 + lr;
  const int gj = j0 + lr;
  const float* pa = (gi < NNODE) ? (es + ((size_t)b * NNODE + gi) * DIM) : ev;
  const float* pb = (gj < NNODE) ? (et + ((size_t)b * NNODE + gj) * DIM) : ev;
  float acc[2][2] = {};
  for (int k0 = 0; k0 < DIM; k0 += 32) {
    float4 av = *(const float4*)(pa + k0 + lk4);
    float4 bv = *(const float4*)(pb + k0 + lk4);
    sA[lr][lk4 + 0] = av.x; sA[lr][lk4 + 1] = av.y;
    sA[lr][lk4 + 2] = av.z; sA[lr][lk4 + 3] = av.w;
    sB[lr][lk4 + 0] = bv.x; sB[lr][lk4 + 1] = bv.y;
    sB[lr][lk4 + 2] = bv.z; sB[lr][lk4 + 3] = bv.w;
    __syncthreads();
#pragma unroll 8
    for (int k = 0; k < 32; ++k) {
      float a0 = sA[ty * 2 + 0][k], a1 = sA[ty * 2 + 1][k];
      float b0 = sB[tx * 2 + 0][k], b1 = sB[tx * 2 + 1][k];
      float d00 = a0 - b0, d01 = a0 - b1, d10 = a1 - b0, d11 = a1 - b1;
      acc[0][0] = fmaf(d00, d00, acc[0][0]);
      acc[0][1] = fmaf(d01, d01, acc[0][1]);
      acc[1][0] = fmaf(d10, d10, acc[1][0]);
      acc[1][1] = fmaf(d11, d11, acc[1][1]);
    }
    __syncthreads();
  }
#pragma unroll
  for (int i = 0; i < 2; ++i) {
    int gi2 = i0 + ty * 2 + i;
#pragma unroll
    for (int j = 0; j < 2; ++j) {
      int gj2 = j0 + tx * 2 + j;
      if (gi2 < NP1 && gj2 < NP1)
        d[(size_t)b * EDSZ + gi2 * NP1 + gj2] = sqrtf(acc[i][j]);
    }
  }
}

// ---------------------------------------------------------------------------
// Deterministic per-batch sum (fp64 tree)
// ---------------------------------------------------------------------------
__global__ __launch_bounds__(256) void batch_sum(
    const float* __restrict__ d, float* __restrict__ sums) {
  const int b = blockIdx.x;
  double s = 0.0;
  for (int idx = threadIdx.x; idx < EDSZ; idx += 256)
    s += (double)d[(size_t)b * EDSZ + idx];
  __shared__ double red[256];
  red[threadIdx.x] = s;
  __syncthreads();
  for (int off = 128; off; off >>= 1) {
    if (threadIdx.x < off) red[threadIdx.x] += red[threadIdx.x + off];
    __syncthreads();
  }
  if (threadIdx.x == 0) sums[b] = (float)red[0];
}

// ---------------------------------------------------------------------------
// normalize: edit = d / sum[b] * N*N
// ---------------------------------------------------------------------------
__global__ __launch_bounds__(256) void normalize_kernel(
    const float* __restrict__ d, const float* __restrict__ sums,
    float* __restrict__ edit) {
  int idx = blockIdx.x * 256 + threadIdx.x;
  if (idx < BATCH * EDSZ) {
    int b = idx / EDSZ;
    edit[idx] = d[idx] / sums[b] * (float)(NNODE * NNODE);
  }
}

// ---------------------------------------------------------------------------
// cross-lane helpers: VALU-pipe (DPP / readlane)
// ---------------------------------------------------------------------------
// Packed (value,col): hi32 = f32 bits of nonneg value, lo32 = column id.
// v_min_f64 on this packing = min by value, ties -> lowest column.
__device__ __forceinline__ double pack_mc(float m, unsigned col) {
  union { double d; unsigned u[2]; } r;
  r.u[0] = col;
  r.u[1] = __float_as_uint(m);
  return r.d;
}

template <int CTRL>
__device__ __forceinline__ double dpp_min_step_pk(double x) {
  union { double d; unsigned long long q; int i[2]; } s, o, r;
  s.d = x;
  o.q = 0x7FEFFFFFFFFFFFFFULL;  // max finite double: identity for packed min
  r.i[0] = __builtin_amdgcn_update_dpp(o.i[0], s.i[0], CTRL, 0xf, 0xf, false);
  r.i[1] = __builtin_amdgcn_update_dpp(o.i[1], s.i[1], CTRL, 0xf, 0xf, false);
  return fmin(x, r.d);
}

// wave64 packed argmin: returns (delta, col) of the global min, uniform.
__device__ __forceinline__ void wave_argmin_pk(double x, float& delta, int& col) {
  x = dpp_min_step_pk<0x111>(x);  // row_shr:1
  x = dpp_min_step_pk<0x112>(x);  // row_shr:2
  x = dpp_min_step_pk<0x114>(x);  // row_shr:4
  x = dpp_min_step_pk<0x118>(x);  // row_shr:8
  x = dpp_min_step_pk<0x142>(x);  // row_bcast:15
  x = dpp_min_step_pk<0x143>(x);  // row_bcast:31
  union { double d; int i[2]; } s;
  s.d = x;
  col = __builtin_amdgcn_readlane(s.i[0], 63);
  delta = __uint_as_float((unsigned)__builtin_amdgcn_readlane(s.i[1], 63));
}

__device__ __forceinline__ float fsel2(float a0, float a1, int s) {
  return (s == 0) ? a0 : a1;
}
__device__ __forceinline__ int isel2(int a0, int a1, int s) {
  return (s == 0) ? a0 : a1;
}

// ---------------------------------------------------------------------------
// LSAPE collapsed to a dense 128x128 LSAP, solved LAPJV-style:
//   Phase 1: column reduction (duals v = column minima + greedy assignment)
//   Phase 1.5: augmenting row reduction (min1/min2 per free row, steal + dual
//              adjust; budget-capped against tie cycling)
//   Phase 2: exact shortest-augmenting-path for remaining free rows.
// ONE WAVE per batch, lane owns 2 columns, VALU-pipe cross-lane ops only.
// Dual feasibility maintained at every hand-off (see round-8 notes): v only
// decreases; ARR rows get u = second-min; displaced rows get u = 0.
// ---------------------------------------------------------------------------
__global__ __launch_bounds__(64) void lsap_kernel(
    const float* __restrict__ edit, float* __restrict__ Aout,
    float* __restrict__ geds) {
  const int b = blockIdx.x;
  const float* ec = edit + (size_t)b * EDSZ;
  float* A = Aout + (size_t)b * EDSZ;
  const int lane = threadIdx.x;
  const int cbase = lane * 2;  // first owned column (0-based), 2 per lane

  __shared__ float D[NNODE * NNODE];  // 64 KB dense collapsed cost

  // stage D = min(sub, del+ins); coalesced global reads (L2-resident)
  for (int idx = lane; idx < NNODE * NNODE; idx += 64) {
    const int i = idx >> 7, j = idx & 127;
    const float sub = ec[i * NP1 + j];
    const float di = ec[i * NP1 + NNODE] + ec[NNODE * NP1 + j];
    D[idx] = fminf(sub, di);
  }
  for (int idx = lane; idx < EDSZ; idx += 64) A[idx] = 0.f;
  __syncthreads();

  // per-lane state: 2 columns (v, minv, way, p) + 2 rows (u)
  float u0 = 0.f, u1 = 0.f;
  float v0 = 0.f, v1 = 0.f;
  float m0, m1;
  int w0 = 0, w1 = 0;
  int p0 = 0, p1 = 0;

  // ---------------- Phase 1: column reduction on dense D ----------------
  int y0 = 0, y1 = 0;
  {
    float c0 = BIGF, c1 = BIGF;
    for (int r = 0; r < NNODE; ++r) {
      const float2 f = *(const float2*)&D[r * NNODE + cbase];
      if (f.x < c0) { c0 = f.x; y0 = r; }
      if (f.y < c1) { c1 = f.y; y1 = r; }
    }
    v0 = c0; v1 = c1;
  }

  // Greedy conflict-free assignment (wave-uniform scalar walk over columns).
  unsigned long long ra0 = 0, ra1 = 0;  // assigned-row bits (0..63, 64..127)
  for (int j = 0; j < NNODE; ++j) {
    const int jl = j >> 1, jq = j & 1;
    const int i1 = __builtin_amdgcn_readlane(isel2(y0, y1, jq), jl);
    const int bit = i1 & 63;
    const unsigned long long msk = (i1 < 64) ? ra0 : ra1;
    if (!((msk >> bit) & 1ull)) {
      if (i1 < 64) ra0 |= 1ull << bit; else ra1 |= 1ull << bit;
      if (lane == jl) {
        if (jq == 0) p0 = i1 + 1;
        else p1 = i1 + 1;
      }
    }
  }

  // ---------------- Phase 1.5: augmenting row reduction ----------------
  {
    const int nfree0 =
        NNODE - __builtin_popcountll(ra0) - __builtin_popcountll(ra1);
    const int budget = 2 * nfree0 + 8;
    for (int step = 0; step < budget; ++step) {
      const unsigned long long fm0 = ~ra0, fm1 = ~ra1;
      int i;
      if (fm0) i = __builtin_ctzll(fm0);
      else if (fm1) i = 64 + __builtin_ctzll(fm1);
      else break;

      const float2 f = *(const float2*)&D[i * NNODE + cbase];
      const float r0 = fmaxf(f.x - v0, 0.f);
      const float r1 = fmaxf(f.y - v1, 0.f);
      const double l0 = pack_mc(r0, cbase + 0);
      const double l1 = pack_mc(r1, cbase + 1);
      float u1v; int j1;
      wave_argmin_pk(fmin(l0, l1), u1v, j1);
      // mask winner, find second min
      const double l0b = (cbase + 0 == j1) ? pack_mc(BIGF, cbase + 0) : l0;
      const double l1b = (cbase + 1 == j1) ? pack_mc(BIGF, cbase + 1) : l1;
      float u2v; int j2;
      wave_argmin_pk(fmin(l0b, l1b), u2v, j2);

      int i1 = __builtin_amdgcn_readlane(isel2(p0, p1, j1 & 1), j1 >> 1);
      int jt = j1;
      if (u1v < u2v) {
        const float dv = u2v - u1v;
        if (lane == (j1 >> 1)) {
          if ((j1 & 1) == 0) v0 -= dv; else v1 -= dv;
        }
      } else if (i1 != 0) {
        jt = j2;
        i1 = __builtin_amdgcn_readlane(isel2(p0, p1, j2 & 1), j2 >> 1);
      }
      // assign row i -> column jt; u[i] = u2v (dual-feasible; see notes)
      if (lane == (jt >> 1)) {
        if ((jt & 1) == 0) p0 = i + 1; else p1 = i + 1;
      }
      if (lane == (i >> 1)) {
        if ((i & 1) == 0) u0 = u2v; else u1 = u2v;
      }
      if (i < 64) ra0 |= 1ull << i; else ra1 |= 1ull << (i - 64);
      if (i1 != 0) {
        const int rr = i1 - 1;
        if (rr < 64) ra0 &= ~(1ull << rr); else ra1 &= ~(1ull << (rr - 64));
        if (lane == (rr >> 1)) {  // freed row: reset dual (still feasible)
          if ((rr & 1) == 0) u0 = 0.f; else u1 = 0.f;
        }
      }
    }
  }

  // ---------------- Phase 2: SAP for each remaining free row ----------------
  for (int ii = 0; ii < NNODE; ++ii) {
    const unsigned long long amsk = (ii < 64) ? ra0 : ra1;
    if ((amsk >> (ii & 63)) & 1ull) continue;  // assigned in phase 1/1.5
    const int i = ii + 1;

    unsigned cused = 0, rused = 0;
    m0 = m1 = BIGF;
    int j0 = 0;       // current column (0 = dummy start)
    int i0 = i;       // p[0] = i
    for (int guard = 0; guard <= NNODE; ++guard) {
      // --- mark used: column j0 (skip dummy col 0) and its row i0 ---
      if (j0 > 0 && lane == ((j0 - 1) >> 1)) {
        if (((j0 - 1) & 1) == 0) { cused |= 1u; m0 = BIGF; }
        else { cused |= 2u; m1 = BIGF; }
      }
      if (lane == ((i0 - 1) >> 1)) rused |= 1u << ((i0 - 1) & 1);

      // --- broadcast u[i0] from owning lane (i0 uniform -> readlane) ---
      const float u_i0 = __uint_as_float((unsigned)__builtin_amdgcn_readlane(
          (int)__float_as_uint(fsel2(u0, u1, (i0 - 1) & 1)), (i0 - 1) >> 1));

      // --- dense cost row: one float2 per lane, no special cases ---
      const float2 f = *(const float2*)&D[(i0 - 1) * NNODE + cbase];

      // --- relax free columns; clamp >=0 keeps packed ordering sound ---
      const bool f0 = !(cused & 1u), f1 = !(cused & 2u);
      {
        float cur = fmaxf(f.x - u_i0 - v0, 0.f);
        bool up = f0 && (cur < m0);
        m0 = up ? cur : m0; w0 = up ? j0 : w0;
      }
      {
        float cur = fmaxf(f.y - u_i0 - v1, 0.f);
        bool up = f1 && (cur < m1);
        m1 = up ? cur : m1; w1 = up ? j0 : w1;
      }

      // --- packed local min (ties -> lowest col), then wave argmin ---
      const double loc = fmin(pack_mc(m0, cbase + 0), pack_mc(m1, cbase + 1));
      float delta; int jcol;
      wave_argmin_pk(loc, delta, jcol);
      const int j1 = jcol + 1;

      // --- dual updates (registers only) ---
      if (!f0) v0 -= delta; else m0 = fmaxf(m0 - delta, 0.f);
      if (!f1) v1 -= delta; else m1 = fmaxf(m1 - delta, 0.f);
      if (rused & 1u) u0 += delta;
      if (rused & 2u) u1 += delta;

      // --- next (or break on free column) ---
      const int pj1 = __builtin_amdgcn_readlane(
          isel2(p0, p1, (j1 - 1) & 1), (j1 - 1) >> 1);
      j0 = j1;
      if (pj1 == 0) break;
      i0 = pj1;
    }

    // --- augment along way[] chain (uniform walk via readlane) ---
    int jc = j0;
    while (jc != 0) {
      const int cl = (jc - 1) >> 1, cq = (jc - 1) & 1;
      const int jp = __builtin_amdgcn_readlane(isel2(w0, w1, cq), cl);
      const int js = (jp == 0) ? 1 : jp;  // safe index for speculative readlane
      const int pvr = __builtin_amdgcn_readlane(
          isel2(p0, p1, (js - 1) & 1), (js - 1) >> 1);
      const int pv = (jp == 0) ? i : pvr;
      if (lane == cl) {
        if (cq == 0) p0 = pv;
        else p1 = pv;
      }
      jc = jp;
    }
  }

  // --- emit A and geds: column j assigned row p[j+1]-1; re-split branches ---
  double contrib = 0.0;
  {
    const int pr[2] = {p0, p1};
#pragma unroll
    for (int q = 0; q < 2; ++q) {
      const int j = cbase + q;
      const int i = pr[q] - 1;
      const float sub = ec[i * NP1 + j];
      const float di = ec[i * NP1 + NNODE] + ec[NNODE * NP1 + j];
      if (sub < di) {
        A[i * NP1 + j] = 1.f;
        contrib += (double)sub;
      } else {
        A[i * NP1 + NNODE] = 1.f;    // delete row i
        A[NNODE * NP1 + j] = 1.f;    // insert col j
        contrib += (double)di;
      }
    }
  }
#pragma unroll
  for (int off = 32; off; off >>= 1) contrib += __shfl_xor(contrib, off);
  if (lane == 0) geds[b] = (float)(contrib / 256.0);
}

// ---------------------------------------------------------------------------
// launch
// ---------------------------------------------------------------------------
extern "C" void kernel_launch(void* const* d_in, const int* in_sizes, int n_in,
                              void* d_out, int out_size, void* d_ws, size_t ws_size,
                              hipStream_t stream) {
  const float* x_s  = (const float*)d_in[0];
  const float* x_t  = (const float*)d_in[1];
  const float* W1   = (const float*)d_in[2];
  const float* b1   = (const float*)d_in[3];
  const float* W2   = (const float*)d_in[4];
  const float* b2   = (const float*)d_in[5];
  const float* virt = (const float*)d_in[6];

  const int M = BATCH * NNODE;  // 2048

  float* ws    = (float*)d_ws;
  float* h_s   = ws;
  float* h_t   = h_s + (size_t)M * DIM;
  float* e_s   = h_t + (size_t)M * DIM;
  float* e_t   = e_s + (size_t)M * DIM;
  float* h_v   = e_t + (size_t)M * DIM;
  float* e_v   = h_v + DIM;
  float* d_raw = e_v + DIM;
  float* sums  = d_raw + (size_t)BATCH * EDSZ;

  float* Aout = (float*)d_out;
  float* edit = Aout + (size_t)BATCH * EDSZ;
  float* geds = edit + (size_t)BATCH * EDSZ;

  dim3 gblk(M / 64, DIM / 64);
  gemm_nt_relu<<<gblk, 256, 0, stream>>>(x_s, W1, b1, h_s, M, DIM, DIM);
  gemm_nt_relu<<<gblk, 256, 0, stream>>>(x_t, W1, b1, h_t, M, DIM, DIM);
  vec_gemm_relu<<<1, 256, 0, stream>>>(virt, W1, b1, h_v);
  gemm_nt_relu<<<gblk, 256, 0, stream>>>(h_s, W2, b2, e_s, M, DIM, DIM);
  gemm_nt_relu<<<gblk, 256, 0, stream>>>(h_t, W2, b2, e_t, M, DIM, DIM);
  vec_gemm_relu<<<1, 256, 0, stream>>>(h_v, W2, b2, e_v);

  cdist_kernel<<<dim3(5, 5, BATCH), 256, 0, stream>>>(e_s, e_t, e_v, d_raw);
  batch_sum<<<BATCH, 256, 0, stream>>>(d_raw, sums);
  normalize_kernel<<<(BATCH * EDSZ + 255) / 256, 256, 0, stream>>>(d_raw, sums, edit);
  lsap_kernel<<<BATCH, 64, 0, stream>>>(edit, Aout, geds);
}